// Round 7
// baseline (385.390 us; speedup 1.0000x reference)
//
#include <hip/hip_runtime.h>
#include <cstdint>

#define D 128
#define T 64
#define B 512
#define EPSF 1e-5f

// wave-uniform lane broadcast via v_readlane
__device__ __forceinline__ float lane_bcast(float x, int l) {
    return __int_as_float(__builtin_amdgcn_readlane(__float_as_int(x), l));
}

// col-pair layout (R3/R5-proven): cpair[j][i2] = (v[i2][j], v[i2+64][j])
// at float2-index j*64 + (i2 ^ ((j&7)<<1)).
__device__ __forceinline__ float2 colpair(const float* csh, int j, int i2) {
    int f2 = j * 64 + (i2 ^ ((j & 7) << 1));
    return *(const float2*)(csh + 2 * f2);
}

// ---------------------------------------------------------------------------
// prep: writes swizzled column-pair matrix csw (16384 f), vd (128), absb (128)
// ---------------------------------------------------------------------------
__global__ __launch_bounds__(64) void prep_kernel(const float* __restrict__ W,
                                                  const float* __restrict__ b,
                                                  float* __restrict__ csw,
                                                  float* __restrict__ vd,
                                                  float* __restrict__ absb) {
    const int i = blockIdx.x;
    const int l = threadIdx.x;
    float w0 = W[i * D + l];
    float w1 = W[i * D + l + 64];
    float p = w0 * w0 + w1 * w1;
#pragma unroll
    for (int off = 32; off; off >>= 1) p += __shfl_xor(p, off);
    float norm = sqrtf(p);
    float scale = norm > 1e-12f ? norm : 1e-12f;
    float v0 = w0 / scale;   // v[i][l]
    float v1 = w1 / scale;   // v[i][l+64]
    const int i2 = i & 63, half = i >> 6;
    const int sw = (l & 7) << 1;              // ((l+64)&7)<<1 == sw
    csw[2 * (l * 64 + (i2 ^ sw)) + half] = v0;
    csw[2 * ((l + 64) * 64 + (i2 ^ sw)) + half] = v1;
    if (i < 64) { if (l == i) vd[i] = v0; }
    else        { if (l == i - 64) vd[i] = v1; }
    if (i == 0) {
        absb[l] = fabsf(b[l]);
        absb[l + 64] = fabsf(b[l + 64]);
    }
}

// ---------------------------------------------------------------------------
// main RNN kernel: ONE wave per block, TWO batches per wave (2blk, 2blk+1).
// Lane owns rows (lane, lane+64) of both batches. All LDS v-reads shared.
// ---------------------------------------------------------------------------
__global__ __launch_bounds__(64) void rnn_kernel(const float* __restrict__ input,
                                                 const float* __restrict__ target,
                                                 const float* __restrict__ returns,
                                                 const float* __restrict__ cswg,
                                                 const float* __restrict__ vdg,
                                                 const float* __restrict__ absbg,
                                                 float* __restrict__ out) {
    __shared__ float csh[D * D];                 // 64 KB col-pairs
    __shared__ __align__(16) float xsA[128];     // x (k-order), batch A
    __shared__ __align__(16) float xsB[128];
    __shared__ __align__(16) float ssA[128];     // (s_lo,s_hi) interleaved
    __shared__ __align__(16) float ssB[128];
    __shared__ __align__(16) float aes[128];     // (aeps_lo,aeps_hi) interleaved

    const int lane = threadIdx.x;
    const int bA = blockIdx.x * 2;               // batches bA, bA+1
    const int rlo = lane, rhi = lane + 64;

    // stage csh (single wave, no barrier needed)
    {
        const float4* src = (const float4*)cswg;
        float4* dst = (float4*)csh;
#pragma unroll
        for (int c = 0; c < 64; ++c) dst[c * 64 + lane] = src[c * 64 + lane];
    }

    const float tgt_lo = target[rlo], tgt_hi = target[rhi];
    const float a_lo = absbg[rlo], a_hi = absbg[rhi];
    const float aeps_lo = a_lo + EPSF, aeps_hi = a_hi + EPSF;
    const float vd_lo = vdg[rlo], vd_hi = vdg[rhi];
    const float rvd_lo = 1.0f / vd_lo, rvd_hi = 1.0f / vd_hi;
    *(float2*)&aes[2 * lane] = make_float2(aeps_lo, aeps_hi);

    // matvec base pointers: column k read at cb[k&7] + k*512 bytes
    const char* cb[8];
#pragma unroll
    for (int c = 0; c < 8; ++c) cb[c] = (const char*)csh + 8 * (lane ^ (c << 1));

    float2 hL = *(const float2*)&input[rlo * T * B + bA];
    float2 hH = *(const float2*)&input[rhi * T * B + bA];
    *(float2*)&out[rlo * T * B + bA] = hL;
    *(float2*)&out[rhi * T * B + bA] = hH;
    float hA_lo = hL.x, hB_lo = hL.y, hA_hi = hH.x, hB_hi = hH.y;

    float2 r2L = *(const float2*)&returns[rlo * T * B + bA];
    float2 r2H = *(const float2*)&returns[rhi * T * B + bA];
    float rA_lo = r2L.x, rB_lo = r2L.y, rA_hi = r2H.x, rB_hi = r2H.y;

    for (int t = 1; t < T; ++t) {
        // ---- adj = h*(1+r)/(1 + sum(h*r)), both batches interleaved ----
        float pA = hA_lo * rA_lo + hA_hi * rA_hi;
        float pB = hB_lo * rB_lo + hB_hi * rB_hi;
#pragma unroll
        for (int off = 32; off; off >>= 1) {
            pA += __shfl_xor(pA, off);
            pB += __shfl_xor(pB, off);
        }
        float rdA = 1.0f / (1.0f + pA);
        float rdB = 1.0f / (1.0f + pB);
        float adjA_lo = hA_lo * (1.0f + rA_lo) * rdA;
        float adjA_hi = hA_hi * (1.0f + rA_hi) * rdA;
        float adjB_lo = hB_lo * (1.0f + rB_lo) * rdB;
        float adjB_hi = hB_hi * (1.0f + rB_hi) * rdB;

        if (t < T - 1) {
            r2L = *(const float2*)&returns[rlo * T * B + t * B + bA];
            r2H = *(const float2*)&returns[rhi * T * B + t * B + bA];
            rA_lo = r2L.x; rB_lo = r2L.y; rA_hi = r2H.x; rB_hi = r2H.y;
        }

        // x staging for uniform-broadcast matvec reads
        float xA_lo = adjA_lo - tgt_lo, xA_hi = adjA_hi - tgt_hi;
        float xB_lo = adjB_lo - tgt_lo, xB_hi = adjB_hi - tgt_hi;
        xsA[lane] = xA_lo; xsA[64 + lane] = xA_hi;
        xsB[lane] = xB_lo; xsB[64 + lane] = xB_hi;

        // ---- s = v @ x: one shared b64 v-read feeds 4 FMAs ----
        float aL0 = 0, aL1 = 0, aH0 = 0, aH1 = 0;
        float bL0 = 0, bL1 = 0, bH0 = 0, bH1 = 0;
#pragma unroll
        for (int m = 0; m < 32; ++m) {
            float4 xA4 = *(const float4*)&xsA[4 * m];
            float4 xB4 = *(const float4*)&xsB[4 * m];
#pragma unroll
            for (int e = 0; e < 4; ++e) {
                const int k = 4 * m + e;
                float2 vp = *(const float2*)(cb[k & 7] + k * 512);
                float xa = (&xA4.x)[e], xb = (&xB4.x)[e];
                if (e & 1) {
                    aL1 = fmaf(vp.x, xa, aL1); aH1 = fmaf(vp.y, xa, aH1);
                    bL1 = fmaf(vp.x, xb, bL1); bH1 = fmaf(vp.y, xb, bH1);
                } else {
                    aL0 = fmaf(vp.x, xa, aL0); aH0 = fmaf(vp.y, xa, aH0);
                    bL0 = fmaf(vp.x, xb, bL0); bH0 = fmaf(vp.y, xb, bH0);
                }
            }
        }
        float sA_lo = aL0 + aL1, sA_hi = aH0 + aH1;
        float sB_lo = bL0 + bL1, sB_hi = bH0 + bH1;

        hA_lo = adjA_lo; hA_hi = adjA_hi;
        hB_lo = adjB_lo; hB_hi = adjB_hi;

        uint64_t mAlo = __ballot(fabsf(sA_lo) > a_lo);
        uint64_t mAhi = __ballot(fabsf(sA_hi) > a_hi);
        uint64_t mBlo = __ballot(fabsf(sB_lo) > a_lo);
        uint64_t mBhi = __ballot(fabsf(sB_hi) > a_hi);
        bool violA = (mAlo | mAhi) != 0ull;
        bool violB = (mBlo | mBhi) != 0ull;

        if (violA || violB) {
            bool judgeA = true, judgeB = true;
            bool needPJA = false, needPJB = false;
            float dlA = 0, dhA = 0, dlB = 0, dhB = 0;

            if (violA) {
                if (sA_lo > a_lo) dlA = (a_lo - sA_lo) / vd_lo;
                else if (sA_lo < -a_lo) dlA = (-a_lo - sA_lo) / vd_lo;
                if (sA_hi > a_hi) dhA = (a_hi - sA_hi) / vd_hi;
                else if (sA_hi < -a_hi) dhA = (-a_hi - sA_hi) / vd_hi;
                int VA = __popcll(mAlo) + __popcll(mAhi);
                if (VA <= 8) {
                    bool in0 = (sA_lo < aeps_lo) && (sA_lo > -aeps_lo) &&
                               (sA_hi < aeps_hi) && (sA_hi > -aeps_hi);
                    judgeA = (__ballot(in0) == ~0ull);
                    if (!judgeA) {
                        uint64_t tml = mAlo, tmh = mAhi;
                        unsigned bits = 0;
#pragma unroll
                        for (int q = 0; q < 8; ++q) {
                            int j = -1;
                            if (tml) { j = (int)__ffsll((unsigned long long)tml) - 1; tml &= tml - 1; }
                            else if (tmh) { j = 64 + (int)__ffsll((unsigned long long)tmh) - 1; tmh &= tmh - 1; }
                            if (j >= 0) {
                                float dj = lane_bcast((j < 64) ? dlA : dhA, j & 63);
                                float2 cp = colpair(csh, j, lane);
                                float nlo = fmaf(cp.x, dj, sA_lo);
                                float nhi = fmaf(cp.y, dj, sA_hi);
                                bool ok = (nlo < aeps_lo) && (nlo > -aeps_lo) &&
                                          (nhi < aeps_hi) && (nhi > -aeps_hi);
                                bits |= ok ? (1u << q) : 0u;
                            }
                        }
#pragma unroll
                        for (int off = 1; off < 64; off <<= 1)
                            bits &= (unsigned)__shfl_xor((int)bits, off);
                        judgeA = (bits != 0u);
                    }
                } else {
                    needPJA = true;
                }
            }
            if (violB) {
                if (sB_lo > a_lo) dlB = (a_lo - sB_lo) / vd_lo;
                else if (sB_lo < -a_lo) dlB = (-a_lo - sB_lo) / vd_lo;
                if (sB_hi > a_hi) dhB = (a_hi - sB_hi) / vd_hi;
                else if (sB_hi < -a_hi) dhB = (-a_hi - sB_hi) / vd_hi;
                int VB = __popcll(mBlo) + __popcll(mBhi);
                if (VB <= 8) {
                    bool in0 = (sB_lo < aeps_lo) && (sB_lo > -aeps_lo) &&
                               (sB_hi < aeps_hi) && (sB_hi > -aeps_hi);
                    judgeB = (__ballot(in0) == ~0ull);
                    if (!judgeB) {
                        uint64_t tml = mBlo, tmh = mBhi;
                        unsigned bits = 0;
#pragma unroll
                        for (int q = 0; q < 8; ++q) {
                            int j = -1;
                            if (tml) { j = (int)__ffsll((unsigned long long)tml) - 1; tml &= tml - 1; }
                            else if (tmh) { j = 64 + (int)__ffsll((unsigned long long)tmh) - 1; tmh &= tmh - 1; }
                            if (j >= 0) {
                                float dj = lane_bcast((j < 64) ? dlB : dhB, j & 63);
                                float2 cp = colpair(csh, j, lane);
                                float nlo = fmaf(cp.x, dj, sB_lo);
                                float nhi = fmaf(cp.y, dj, sB_hi);
                                bool ok = (nlo < aeps_lo) && (nlo > -aeps_lo) &&
                                          (nhi < aeps_hi) && (nhi > -aeps_hi);
                                bits |= ok ? (1u << q) : 0u;
                            }
                        }
#pragma unroll
                        for (int off = 1; off < 64; off <<= 1)
                            bits &= (unsigned)__shfl_xor((int)bits, off);
                        judgeB = (bits != 0u);
                    }
                } else {
                    needPJB = true;
                }
            }

            // ---- merged parallel judge (V>8): one column pass, both batches ----
            if (needPJA || needPJB) {
                if (needPJA) *(float2*)&ssA[2 * lane] = make_float2(sA_lo, sA_hi);
                if (needPJB) *(float2*)&ssB[2 * lane] = make_float2(sB_lo, sB_hi);
                float m1A = -1.0f, m2A = -1.0f, m1B = -1.0f, m2B = -1.0f;
                const int jx = lane & 7;
                const float* jbase = csh + 128 * lane;
#pragma unroll
                for (int c = 0; c < 32; ++c) {
                    const float* pr = jbase + 4 * (c ^ jx);
                    float4 c1 = *(const float4*)pr;           // col j=lane: rows 2c,2c+64,2c+1,2c+65
                    float4 c2 = *(const float4*)(pr + 8192);  // col j=lane+64
                    float4 ae = *(const float4*)&aes[4 * c];
                    if (needPJA) {
                        float4 sv = *(const float4*)&ssA[4 * c];
                        m1A = fmaxf(m1A, fabsf(fmaf(c1.x, dlA, sv.x)) - ae.x);
                        m1A = fmaxf(m1A, fabsf(fmaf(c1.y, dlA, sv.y)) - ae.y);
                        m1A = fmaxf(m1A, fabsf(fmaf(c1.z, dlA, sv.z)) - ae.z);
                        m1A = fmaxf(m1A, fabsf(fmaf(c1.w, dlA, sv.w)) - ae.w);
                        m2A = fmaxf(m2A, fabsf(fmaf(c2.x, dhA, sv.x)) - ae.x);
                        m2A = fmaxf(m2A, fabsf(fmaf(c2.y, dhA, sv.y)) - ae.y);
                        m2A = fmaxf(m2A, fabsf(fmaf(c2.z, dhA, sv.z)) - ae.z);
                        m2A = fmaxf(m2A, fabsf(fmaf(c2.w, dhA, sv.w)) - ae.w);
                    }
                    if (needPJB) {
                        float4 sv = *(const float4*)&ssB[4 * c];
                        m1B = fmaxf(m1B, fabsf(fmaf(c1.x, dlB, sv.x)) - ae.x);
                        m1B = fmaxf(m1B, fabsf(fmaf(c1.y, dlB, sv.y)) - ae.y);
                        m1B = fmaxf(m1B, fabsf(fmaf(c1.z, dlB, sv.z)) - ae.z);
                        m1B = fmaxf(m1B, fabsf(fmaf(c1.w, dlB, sv.w)) - ae.w);
                        m2B = fmaxf(m2B, fabsf(fmaf(c2.x, dhB, sv.x)) - ae.x);
                        m2B = fmaxf(m2B, fabsf(fmaf(c2.y, dhB, sv.y)) - ae.y);
                        m2B = fmaxf(m2B, fabsf(fmaf(c2.z, dhB, sv.z)) - ae.z);
                        m2B = fmaxf(m2B, fabsf(fmaf(c2.w, dhB, sv.w)) - ae.w);
                    }
                }
                if (needPJA)
                    judgeA = ((__ballot(m1A < 0.0f) | __ballot(m2A < 0.0f)) != 0ull);
                if (needPJB)
                    judgeB = ((__ballot(m1B < 0.0f) | __ballot(m2B < 0.0f)) != 0ull);
            }

            bool swA = violA && judgeA, swB = violB && judgeB;
            bool biA = violA && !judgeA, biB = violB && !judgeB;

            // ---- merged Gauss-Seidel sweep (ascending j per batch) ----
            if (swA || swB) {
                uint64_t remAlo = swA ? ~0ull : 0ull, remAhi = swA ? ~0ull : 0ull;
                uint64_t remBlo = swB ? ~0ull : 0ull, remBhi = swB ? ~0ull : 0ull;
                while (true) {
                    uint64_t vAl = __ballot(fabsf(sA_lo) > a_lo) & remAlo;
                    uint64_t vAh = __ballot(fabsf(sA_hi) > a_hi) & remAhi;
                    uint64_t vBl = __ballot(fabsf(sB_lo) > a_lo) & remBlo;
                    uint64_t vBh = __ballot(fabsf(sB_hi) > a_hi) & remBhi;
                    int jA = -1, jB = -1;
                    if (vAl) jA = (int)__ffsll((unsigned long long)vAl) - 1;
                    else if (vAh) jA = 64 + (int)__ffsll((unsigned long long)vAh) - 1;
                    if (vBl) jB = (int)__ffsll((unsigned long long)vBl) - 1;
                    else if (vBh) jB = 64 + (int)__ffsll((unsigned long long)vBh) - 1;
                    if (jA < 0 && jB < 0) break;
                    // issue both column loads together (one latency)
                    float2 cA = make_float2(0.0f, 0.0f), cB = make_float2(0.0f, 0.0f);
                    if (jA >= 0) cA = colpair(csh, jA, lane);
                    if (jB >= 0) cB = colpair(csh, jB, lane);
                    if (jA >= 0) {
                        if (jA < 64) remAlo = (jA == 63) ? 0ull : (~0ull << (jA + 1));
                        else { remAlo = 0ull; int s = jA - 64;
                               remAhi = (s == 63) ? 0ull : (~0ull << (s + 1)); }
                        float d1 = (sA_lo > a_lo) ? (a_lo - sA_lo) * rvd_lo
                                 : ((sA_lo < -a_lo) ? (-a_lo - sA_lo) * rvd_lo : 0.0f);
                        float d2 = (sA_hi > a_hi) ? (a_hi - sA_hi) * rvd_hi
                                 : ((sA_hi < -a_hi) ? (-a_hi - sA_hi) * rvd_hi : 0.0f);
                        float dj = lane_bcast((jA < 64) ? d1 : d2, jA & 63);
                        if (lane == (jA & 63)) {
                            if (jA < 64) hA_lo += dj; else hA_hi += dj;
                        }
                        sA_lo = fmaf(cA.x, dj, sA_lo);
                        sA_hi = fmaf(cA.y, dj, sA_hi);
                    }
                    if (jB >= 0) {
                        if (jB < 64) remBlo = (jB == 63) ? 0ull : (~0ull << (jB + 1));
                        else { remBlo = 0ull; int s = jB - 64;
                               remBhi = (s == 63) ? 0ull : (~0ull << (s + 1)); }
                        float d1 = (sB_lo > a_lo) ? (a_lo - sB_lo) * rvd_lo
                                 : ((sB_lo < -a_lo) ? (-a_lo - sB_lo) * rvd_lo : 0.0f);
                        float d2 = (sB_hi > a_hi) ? (a_hi - sB_hi) * rvd_hi
                                 : ((sB_hi < -a_hi) ? (-a_hi - sB_hi) * rvd_hi : 0.0f);
                        float dj = lane_bcast((jB < 64) ? d1 : d2, jB & 63);
                        if (lane == (jB & 63)) {
                            if (jB < 64) hB_lo += dj; else hB_hi += dj;
                        }
                        sB_lo = fmaf(cB.x, dj, sB_lo);
                        sB_hi = fmaf(cB.y, dj, sB_hi);
                    }
                }
            }

            // ---- merged bisection (10 iters, s-space lerp) ----
            if (biA || biB) {
                float hinAlo = tgt_lo, hinAhi = tgt_hi, sinAlo = 0, sinAhi = 0;
                float houtAlo = hA_lo, houtAhi = hA_hi, soutAlo = sA_lo, soutAhi = sA_hi;
                float hmAlo = 0, hmAhi = 0;
                float hinBlo = tgt_lo, hinBhi = tgt_hi, sinBlo = 0, sinBhi = 0;
                float houtBlo = hB_lo, houtBhi = hB_hi, soutBlo = sB_lo, soutBhi = sB_hi;
                float hmBlo = 0, hmBhi = 0;
#pragma unroll
                for (int it = 0; it < 10; ++it) {
                    if (biA) {
                        hmAlo = hinAlo + (houtAlo - hinAlo) * 0.5f;
                        hmAhi = hinAhi + (houtAhi - hinAhi) * 0.5f;
                        float smlo = sinAlo + (soutAlo - sinAlo) * 0.5f;
                        float smhi = sinAhi + (soutAhi - sinAhi) * 0.5f;
                        bool ok = (smlo <= aeps_lo) && (smlo >= -aeps_lo) &&
                                  (smhi <= aeps_hi) && (smhi >= -aeps_hi);
                        bool inside = (__ballot(ok) == ~0ull);
                        if (inside) { hinAlo = hmAlo; hinAhi = hmAhi; sinAlo = smlo; sinAhi = smhi; }
                        else { houtAlo = hmAlo; houtAhi = hmAhi; soutAlo = smlo; soutAhi = smhi; }
                    }
                    if (biB) {
                        hmBlo = hinBlo + (houtBlo - hinBlo) * 0.5f;
                        hmBhi = hinBhi + (houtBhi - hinBhi) * 0.5f;
                        float smlo = sinBlo + (soutBlo - sinBlo) * 0.5f;
                        float smhi = sinBhi + (soutBhi - sinBhi) * 0.5f;
                        bool ok = (smlo <= aeps_lo) && (smlo >= -aeps_lo) &&
                                  (smhi <= aeps_hi) && (smhi >= -aeps_hi);
                        bool inside = (__ballot(ok) == ~0ull);
                        if (inside) { hinBlo = hmBlo; hinBhi = hmBhi; sinBlo = smlo; sinBhi = smhi; }
                        else { houtBlo = hmBlo; houtBhi = hmBhi; soutBlo = smlo; soutBhi = smhi; }
                    }
                }
                if (biA) { hA_lo = hmAlo; hA_hi = hmAhi; }
                if (biB) { hB_lo = hmBlo; hB_hi = hmBhi; }
            }
        }
        // no violators in a batch -> judge=1, sweep no-op, h = adj

        *(float2*)&out[rlo * T * B + t * B + bA] = make_float2(hA_lo, hB_lo);
        *(float2*)&out[rhi * T * B + t * B + bA] = make_float2(hA_hi, hB_hi);
    }

    *(float2*)&out[D * T * B + rlo * B + bA] = make_float2(hA_lo, hB_lo);
    *(float2*)&out[D * T * B + rhi * B + bA] = make_float2(hA_hi, hB_hi);
}

extern "C" void kernel_launch(void* const* d_in, const int* in_sizes, int n_in,
                              void* d_out, int out_size, void* d_ws, size_t ws_size,
                              hipStream_t stream) {
    const float* input   = (const float*)d_in[0];
    const float* target  = (const float*)d_in[1];
    const float* returns = (const float*)d_in[2];
    // d_in[3] = hidden (unused by the reference)
    const float* W = (const float*)d_in[4];
    const float* b = (const float*)d_in[5];
    float* out = (float*)d_out;

    float* csw  = (float*)d_ws;            // 16384 floats (col-pair layout)
    float* vd   = csw + D * D;             // 128 floats
    float* absb = vd + D;                  // 128 floats

    prep_kernel<<<D, 64, 0, stream>>>(W, b, csw, vd, absb);
    rnn_kernel<<<B / 2, 64, 0, stream>>>(input, target, returns, csw, vd, absb, out);
}

// Round 8
// 258.992 us; speedup vs baseline: 1.4880x; 1.4880x over previous
//
#include <hip/hip_runtime.h>
#include <cstdint>

#define D 128
#define T 64
#define B 512
#define EPSF 1e-5f

// wave-uniform lane broadcast via v_readlane
__device__ __forceinline__ float lane_bcast(float x, int l) {
    return __int_as_float(__builtin_amdgcn_readlane(__float_as_int(x), l));
}

// ---------------------------------------------------------------------------
// prep: vT[k*D+i] = v[i][k] = W[i][k]/max(norm_i,1e-12); vd[i]=v[i][i]; absb=|b|
// ---------------------------------------------------------------------------
__global__ __launch_bounds__(64) void prep_kernel(const float* __restrict__ W,
                                                  const float* __restrict__ b,
                                                  float* __restrict__ vT,
                                                  float* __restrict__ vd,
                                                  float* __restrict__ absb) {
    const int i = blockIdx.x;
    const int l = threadIdx.x;
    float w0 = W[i * D + l];
    float w1 = W[i * D + l + 64];
    float p = w0 * w0 + w1 * w1;
#pragma unroll
    for (int off = 32; off; off >>= 1) p += __shfl_xor(p, off);
    float norm = sqrtf(p);
    float scale = norm > 1e-12f ? norm : 1e-12f;
    float v0 = w0 / scale;
    float v1 = w1 / scale;
    vT[l * D + i] = v0;
    vT[(l + 64) * D + i] = v1;
    if (i < 64) {
        if (l == i) vd[i] = v0;
    } else {
        if (l == i - 64) vd[i] = v1;
    }
    if (i == 0) {
        absb[l] = fabsf(b[l]);
        absb[l + 64] = fabsf(b[l + 64]);
    }
}

// ---------------------------------------------------------------------------
// main RNN kernel. One wave per batch; lane owns rows (lane, lane+64).
// v stored swizzled in LDS: v[i][k] at vsh[k*128 + (i ^ ((k&7)<<2))].
// Matvec reads b128 ALONG i (4 rows/lane, k split by lane>>5), then a
// shfl reduce + LDS redistribute. Probe/sweep/judge identical to R3.
// ---------------------------------------------------------------------------
__global__ __launch_bounds__(128) void rnn_kernel(const float* __restrict__ input,
                                                  const float* __restrict__ target,
                                                  const float* __restrict__ returns,
                                                  const float* __restrict__ vTg,
                                                  const float* __restrict__ vdg,
                                                  const float* __restrict__ absbg,
                                                  float* __restrict__ out) {
    __shared__ float vsh[D * D];                 // 64 KB swizzled
    __shared__ __align__(16) float xs[2][128];   // per-wave x stage (k-order)
    __shared__ __align__(16) float ss[2][128];   // per-wave s redistribute

    const int tid = threadIdx.x;
    // cooperative swizzled load of vT (plain layout in ws -> swizzled LDS)
    {
        const float4* src = (const float4*)vTg;
        float4* dst = (float4*)vsh;
#pragma unroll
        for (int c = 0; c < 32; ++c) {
            int f = c * 128 + tid;          // source float4 index
            int k = f >> 5;                 // row k of vT
            int i = (f & 31) << 2;          // starting i of this float4
            int ck = (k & 7) << 2;
            int d4 = k * 32 + (((i ^ ck)) >> 2);
            dst[d4] = src[f];
        }
    }
    __syncthreads();

    const int w = tid >> 6;
    const int lane = tid & 63;
    const int b = blockIdx.x * 2 + w;
    const int rlo = lane, rhi = lane + 64;

    const float tgt_lo = target[rlo], tgt_hi = target[rhi];
    const float a_lo = absbg[rlo], a_hi = absbg[rhi];
    const float aeps_lo = a_lo + EPSF, aeps_hi = a_hi + EPSF;
    const float vd_lo = vdg[rlo], vd_hi = vdg[rhi];
    const float rvd_lo = 1.0f / vd_lo, rvd_hi = 1.0f / vd_hi;

    // matvec: lane (m, u) handles rows 4m..4m+3, k in [64u, 64u+64)
    const int m = lane & 31, u = lane >> 5;
    // float4 of rows 4m..4m+3 at column k: byte k*512 + 16*(m ^ (k&7))
    const char* vq[8];
#pragma unroll
    for (int c = 0; c < 8; ++c)
        vq[c] = (const char*)vsh + 16 * (m ^ c) + u * 32768;

    // parallel-judge column bases (R3): candidate j=lane reads float4 at
    // Abase[c] + 32*a  (logical i0 = a*32 + c*4); candidate lane+64 at +8192
    const int cj = (lane & 7) << 2;
    int Abase[8];
#pragma unroll
    for (int c = 0; c < 8; ++c) Abase[c] = lane * 128 + ((c << 2) ^ cj);

    float h_lo = input[rlo * T * B + b];
    float h_hi = input[rhi * T * B + b];
    out[rlo * T * B + b] = h_lo;
    out[rhi * T * B + b] = h_hi;

    float r_lo = returns[rlo * T * B + b];
    float r_hi = returns[rhi * T * B + b];

    for (int t = 1; t < T; ++t) {
        // ---- adj = h*(1+r)/(1 + sum(h*r)) ----
        float num_lo = h_lo * (1.0f + r_lo);
        float num_hi = h_hi * (1.0f + r_hi);
        float p = h_lo * r_lo + h_hi * r_hi;
#pragma unroll
        for (int off = 32; off; off >>= 1) p += __shfl_xor(p, off);
        float rden = 1.0f / (1.0f + p);
        float adj_lo = num_lo * rden;
        float adj_hi = num_hi * rden;

        if (t < T - 1) {
            r_lo = returns[rlo * T * B + t * B + b];
            r_hi = returns[rhi * T * B + t * B + b];
        }

        const float x_lo = adj_lo - tgt_lo;
        const float x_hi = adj_hi - tgt_hi;

        // ---- s = v @ x: b128 along i, 4 rows/lane, k-half per u ----
        xs[w][lane] = x_lo;
        xs[w][64 + lane] = x_hi;
        float ac0 = 0, ac1 = 0, ac2 = 0, ac3 = 0;
#pragma unroll
        for (int q = 0; q < 16; ++q) {
            float4 x4 = *(const float4*)&xs[w][64 * u + 4 * q];
#pragma unroll
            for (int e = 0; e < 4; ++e) {
                const int kk = 4 * q + e;
                float4 vv = *(const float4*)(vq[kk & 7] + kk * 512);
                float xe = (&x4.x)[e];
                ac0 = fmaf(vv.x, xe, ac0);
                ac1 = fmaf(vv.y, xe, ac1);
                ac2 = fmaf(vv.z, xe, ac2);
                ac3 = fmaf(vv.w, xe, ac3);
            }
        }
        ac0 += __shfl_xor(ac0, 32);
        ac1 += __shfl_xor(ac1, 32);
        ac2 += __shfl_xor(ac2, 32);
        ac3 += __shfl_xor(ac3, 32);
        if (u == 0) *(float4*)&ss[w][4 * m] = make_float4(ac0, ac1, ac2, ac3);
        float s_lo = ss[w][lane];
        float s_hi = ss[w][64 + lane];

        h_lo = adj_lo;
        h_hi = adj_hi;

        bool viol_lo = (s_lo > a_lo) || (s_lo < -a_lo);
        bool viol_hi = (s_hi > a_hi) || (s_hi < -a_hi);
        uint64_t mlo = __ballot(viol_lo);
        uint64_t mhi = __ballot(viol_hi);

        if ((mlo | mhi) != 0ull) {
            // per-lane deltas (reference lam formulas, IEEE div)
            float dl = 0.0f, dh = 0.0f;
            if (s_lo > a_lo) dl = (a_lo - s_lo) / vd_lo;
            else if (s_lo < -a_lo) dl = (-a_lo - s_lo) / vd_lo;
            if (s_hi > a_hi) dh = (a_hi - s_hi) / vd_hi;
            else if (s_hi < -a_hi) dh = (-a_hi - s_hi) / vd_hi;

            int V = __popcll(mlo) + __popcll(mhi);
            bool judge = false;

            if (V <= 8) {
                // q0 shortcut (valid: V<128 so a zero-delta candidate exists)
                bool in_lo = (s_lo < aeps_lo) && (s_lo > -aeps_lo);
                bool in_hi = (s_hi < aeps_hi) && (s_hi > -aeps_hi);
                judge = (__ballot(in_lo && in_hi) == ~0ull);
                if (!judge) {
                    // batch-prefetch all candidate columns, then test
                    uint64_t tml = mlo, tmh = mhi;
                    int jn[8];
                    float djs[8];
                    float2 cps[8];
#pragma unroll
                    for (int q = 0; q < 8; ++q) {
                        int j = -1;
                        if (tml) {
                            j = (int)__ffsll((unsigned long long)tml) - 1;
                            tml &= tml - 1;
                        } else if (tmh) {
                            j = 64 + (int)__ffsll((unsigned long long)tmh) - 1;
                            tmh &= tmh - 1;
                        }
                        jn[q] = j;
                        if (j >= 0) {
                            djs[q] = lane_bcast((j < 64) ? dl : dh, j & 63);
                            int cjj = (j & 7) << 2;
                            int base = j * 128 + (rlo ^ cjj);
                            cps[q] = make_float2(vsh[base], vsh[base + 64]);
                        }
                    }
#pragma unroll
                    for (int q = 0; q < 8; ++q) {
                        if (jn[q] >= 0 && !judge) {
                            float n_lo = fmaf(cps[q].x, djs[q], s_lo);
                            float n_hi = fmaf(cps[q].y, djs[q], s_hi);
                            bool pl = (n_lo < aeps_lo) && (n_lo > -aeps_lo);
                            bool ph = (n_hi < aeps_hi) && (n_hi > -aeps_hi);
                            if (__ballot(pl && ph) == ~0ull) judge = true;
                        }
                    }
                }
            } else {
                // ---- parallel judge: lane tests candidates j=lane, lane+64 ----
                float m1 = -1.0f, m2 = -1.0f;   // only the sign of max matters
#pragma unroll
                for (int a = 0; a < 4; ++a) {
#pragma unroll
                    for (int c = 0; c < 8; ++c) {
                        const int i0 = a * 32 + c * 4;
                        const float* p1 = &vsh[Abase[c] + 32 * a];
                        float4 c1 = *(const float4*)p1;
                        float4 c2 = *(const float4*)(p1 + 8192);
#pragma unroll
                        for (int e = 0; e < 4; ++e) {
                            const int i = i0 + e;
                            float sv = (i < 64) ? lane_bcast(s_lo, i)
                                                : lane_bcast(s_hi, i - 64);
                            float ae = (i < 64) ? lane_bcast(aeps_lo, i)
                                                : lane_bcast(aeps_hi, i - 64);
                            float f1 = ((const float*)&c1)[e];
                            float f2 = ((const float*)&c2)[e];
                            m1 = fmaxf(m1, fabsf(fmaf(f1, dl, sv)) - ae);
                            m2 = fmaxf(m2, fabsf(fmaf(f2, dh, sv)) - ae);
                        }
                    }
                }
                judge = ((__ballot(m1 < 0.0f) | __ballot(m2 < 0.0f)) != 0ull);
            }

            if (judge) {
                // ---- Gauss-Seidel sweep (ascending j, violators only) ----
                uint64_t rem_lo = ~0ull, rem_hi = ~0ull;
                while (true) {
                    uint64_t m1b = __ballot((s_lo > a_lo) || (s_lo < -a_lo)) & rem_lo;
                    uint64_t m2b = __ballot((s_hi > a_hi) || (s_hi < -a_hi)) & rem_hi;
                    int j;
                    if (m1b) {
                        int jl = (int)__ffsll((unsigned long long)m1b) - 1;
                        j = jl;
                        rem_lo = (jl == 63) ? 0ull : (~0ull << (jl + 1));
                    } else if (m2b) {
                        int jh = (int)__ffsll((unsigned long long)m2b) - 1;
                        j = 64 + jh;
                        rem_lo = 0ull;
                        rem_hi = (jh == 63) ? 0ull : (~0ull << (jh + 1));
                    } else {
                        break;
                    }
                    float dl2 = (s_lo > a_lo) ? (a_lo - s_lo) * rvd_lo
                               : ((s_lo < -a_lo) ? (-a_lo - s_lo) * rvd_lo : 0.0f);
                    float dh2 = (s_hi > a_hi) ? (a_hi - s_hi) * rvd_hi
                               : ((s_hi < -a_hi) ? (-a_hi - s_hi) * rvd_hi : 0.0f);
                    float srcv = (j < 64) ? dl2 : dh2;
                    float dj = lane_bcast(srcv, j & 63);
                    if (lane == (j & 63)) {
                        if (j < 64) h_lo += dj; else h_hi += dj;
                    }
                    int cjj = (j & 7) << 2;
                    int base = j * 128 + (rlo ^ cjj);
                    s_lo = fmaf(vsh[base], dj, s_lo);
                    s_hi = fmaf(vsh[base + 64], dj, s_hi);
                }
            } else {
                // ---- bisection between pi_bar (s=0) and adj (s), s-space ----
                float hin_lo = tgt_lo, hin_hi = tgt_hi;
                float sin_lo = 0.0f, sin_hi = 0.0f;
                float hout_lo = h_lo, hout_hi = h_hi;
                float sout_lo = s_lo, sout_hi = s_hi;
                float hm_lo = 0.0f, hm_hi = 0.0f;
#pragma unroll
                for (int it = 0; it < 10; ++it) {
                    hm_lo = hin_lo + (hout_lo - hin_lo) * 0.5f;
                    hm_hi = hin_hi + (hout_hi - hin_hi) * 0.5f;
                    float sm_lo = sin_lo + (sout_lo - sin_lo) * 0.5f;
                    float sm_hi = sin_hi + (sout_hi - sin_hi) * 0.5f;
                    bool pl = (sm_lo <= aeps_lo) && (sm_lo >= -aeps_lo);
                    bool ph = (sm_hi <= aeps_hi) && (sm_hi >= -aeps_hi);
                    bool inside = (__ballot(pl && ph) == ~0ull);
                    if (inside) {
                        hin_lo = hm_lo; hin_hi = hm_hi;
                        sin_lo = sm_lo; sin_hi = sm_hi;
                    } else {
                        hout_lo = hm_lo; hout_hi = hm_hi;
                        sout_lo = sm_lo; sout_hi = sm_hi;
                    }
                }
                h_lo = hm_lo;
                h_hi = hm_hi;
            }
        }
        // else: no violators -> judge=1, sweep no-op, h = adj unchanged

        out[rlo * T * B + t * B + b] = h_lo;
        out[rhi * T * B + t * B + b] = h_hi;
    }

    out[D * T * B + rlo * B + b] = h_lo;
    out[D * T * B + rhi * B + b] = h_hi;
}

extern "C" void kernel_launch(void* const* d_in, const int* in_sizes, int n_in,
                              void* d_out, int out_size, void* d_ws, size_t ws_size,
                              hipStream_t stream) {
    const float* input   = (const float*)d_in[0];
    const float* target  = (const float*)d_in[1];
    const float* returns = (const float*)d_in[2];
    // d_in[3] = hidden (unused by the reference)
    const float* W = (const float*)d_in[4];
    const float* b = (const float*)d_in[5];
    float* out = (float*)d_out;

    float* vT   = (float*)d_ws;            // 16384 floats
    float* vd   = vT + D * D;              // 128 floats
    float* absb = vd + D;                  // 128 floats

    prep_kernel<<<D, 64, 0, stream>>>(W, b, vT, vd, absb);
    rnn_kernel<<<B / 2, 128, 0, stream>>>(input, target, returns, vT, vd, absb, out);
}